// Round 13
// baseline (96.408 us; speedup 1.0000x reference)
//
#include <hip/hip_runtime.h>

#define NB 2
#define CIN 256
#define HH 64
#define WW 64
#define CCMP 64
#define HO 128
#define WO 128

// padded comp layout: [n][c][66][66], interior at (+1,+1)
#define CPLD 66
#define CPCH (CPLD * CPLD)          // 4356
#define CPIMG (CCMP * CPCH)         // 278784
#define CPTOT (NB * CPIMG)          // 557568 floats

// ws layout (floats)
#define OFF_OFFA  (CPTOT)
#define OFF_KERA  (OFF_OFFA + 65536)
#define OFF_OFFB2 (OFF_KERA + 204800)
#define OFF_KERB2 (OFF_OFFB2 + 65536)
#define OFF_WTS   (OFF_KERB2 + 204800)

// ---------------- k1: 1x1 conv -> comp_pad interior; also zeroes its halo ----------------
// 512 blocks: (n, ccg of 16, hq of 16); 4 oc/thread (2 waves/SIMD).
__global__ __launch_bounds__(256) void k1_comp(const float* __restrict__ x,
                                               const float* __restrict__ wc,
                                               const float* __restrict__ bc,
                                               float* __restrict__ comp_pad) {
  int b = blockIdx.x;
  int n = b >> 8;
  int ccg = (b >> 4) & 15;
  int hq = b & 15;
  int hsub = threadIdx.x >> 6;
  int w = threadIdx.x & 63;
  int h = hq * 4 + hsub;

  float acc[4];
#pragma unroll
  for (int j = 0; j < 4; ++j) acc[j] = bc[ccg * 4 + j];
  const float* xp = x + ((size_t)(n * CIN) * HH + h) * WW + w;
#pragma unroll 4
  for (int c = 0; c < CIN; ++c) {
    float xv = xp[(size_t)c * HH * WW];
#pragma unroll
    for (int j = 0; j < 4; ++j) acc[j] += xv * wc[(ccg * 4 + j) * CIN + c];
  }
  float* plane = comp_pad + (size_t)n * CPIMG + (size_t)(ccg * 4) * CPCH;
#pragma unroll
  for (int j = 0; j < 4; ++j)
    plane[(size_t)j * CPCH + (h + 1) * CPLD + (w + 1)] = acc[j];

  // halo zeroing for this block's 4 channel planes
  if (threadIdx.x < 32) {
    int ch = threadIdx.x >> 3;
    int rw = (threadIdx.x >> 1) & 3;
    int side = threadIdx.x & 1;
    plane[(size_t)ch * CPCH + (hq * 4 + rw + 1) * CPLD + side * 65] = 0.f;
  }
  if (hq == 0)
    for (int i = threadIdx.x; i < 4 * CPLD; i += 256)
      plane[(size_t)(i / CPLD) * CPCH + (i % CPLD)] = 0.f;               // top row
  if (hq == 15)
    for (int i = threadIdx.x; i < 4 * CPLD; i += 256)
      plane[(size_t)(i / CPLD) * CPCH + 65 * CPLD + (i % CPLD)] = 0.f;   // bottom row
}

// ------------- k2: fused 3x3 convs, c-SPLIT: each block reduces 32 channels -------------
// 1088 blocks: (n, half, ocp of 17, hq of 16) -> 4.25 waves/SIMD. half0 -> A(+bias), half1 -> B.
__global__ __launch_bounds__(256) void k2_conv3(const float* __restrict__ comp_pad,
                                                const float* __restrict__ w_off,
                                                const float* __restrict__ b_off,
                                                const float* __restrict__ w_ker,
                                                const float* __restrict__ b_ker,
                                                float* __restrict__ offb_a,
                                                float* __restrict__ kerb_a,
                                                float* __restrict__ offb_b,
                                                float* __restrict__ kerb_b) {
  int b = blockIdx.x;
  int n = b / 544;
  int r = b % 544;
  int half = r / 272;
  int r2 = r % 272;
  int ocp = r2 / 16;
  int hq = r2 % 16;
  int hsub = threadIdx.x >> 6;
  int w = threadIdx.x & 63;
  int h = hq * 4 + hsub;

  int oc0 = ocp * 2;
  int oc1 = (oc0 + 1 < 33) ? oc0 + 1 : 32;
  const float* wp0 = (oc0 < 8) ? (w_off + (size_t)oc0 * CCMP * 9)
                               : (w_ker + (size_t)(oc0 - 8) * CCMP * 9);
  const float* wp1 = (oc1 < 8) ? (w_off + (size_t)oc1 * CCMP * 9)
                               : (w_ker + (size_t)(oc1 - 8) * CCMP * 9);
  float a0 = 0.f, a1 = 0.f;
  if (half == 0) {
    a0 = (oc0 < 8) ? b_off[oc0] : b_ker[oc0 - 8];
    a1 = (oc1 < 8) ? b_off[oc1] : b_ker[oc1 - 8];
  }

  const float* base = comp_pad + (size_t)n * CPIMG + h * CPLD + w;
  int cbeg = half * 32;

  for (int cb = cbeg; cb < cbeg + 32; cb += 4) {
    float t[4][9];
#pragma unroll
    for (int cc = 0; cc < 4; ++cc) {
      const float* p = base + (size_t)(cb + cc) * CPCH;
#pragma unroll
      for (int dy = 0; dy < 3; ++dy)
#pragma unroll
        for (int dx = 0; dx < 3; ++dx)
          t[cc][dy * 3 + dx] = p[dy * CPLD + dx];
    }
#pragma unroll
    for (int cc = 0; cc < 4; ++cc)
#pragma unroll
      for (int k = 0; k < 9; ++k) {
        float tv = t[cc][k];
        a0 += tv * wp0[(cb + cc) * 9 + k];
        a1 += tv * wp1[(cb + cc) * 9 + k];
      }
  }

  float* offd = half ? offb_b : offb_a;
  float* kerd = half ? kerb_b : kerb_a;
  int pos = h * WW + w;
  if (oc0 < 8) offd[(size_t)(n * 8 + oc0) * 4096 + pos] = a0;
  else         kerd[(size_t)(n * 25 + (oc0 - 8)) * 4096 + pos] = a0;
  if (oc1 < 8) offd[(size_t)(n * 8 + oc1) * 4096 + pos] = a1;
  else         kerd[(size_t)(n * 25 + (oc1 - 8)) * 4096 + pos] = a1;
}

// ------- k34: sum partials + softmax + bilinear sample -> wts[n][h][pq][k][w] -------
// 512 blocks x 64 threads (2 blocks/CU).
__global__ __launch_bounds__(64, 2) void k34_wts(const float* __restrict__ offb_a,
                                                 const float* __restrict__ offb_b,
                                                 const float* __restrict__ kerb_a,
                                                 const float* __restrict__ kerb_b,
                                                 float* __restrict__ wts) {
  int t = blockIdx.x * 64 + threadIdx.x;    // 32768 threads: (n, ho, wo)
  int n = t >> 14;
  int r = t & 16383;
  int ho = r >> 7;
  int wo = r & 127;
  int h = ho >> 1, p = ho & 1, w = wo >> 1, q = wo & 1;
  int pq = p * 2 + q;
  size_t oix = ((size_t)(n * 8 + pq) * HH + h) * WW + w;
  size_t oiy = ((size_t)(n * 8 + 4 + pq) * HH + h) * WW + w;
  float offx = offb_a[oix] + offb_b[oix];
  float offy = offb_a[oiy] + offb_b[oiy];
  // align_corners=True + border clamp algebra: sample at (h+offy, w+offx)
  float ix = fminf(fmaxf((float)w + offx, 0.f), 63.f);
  float iy = fminf(fmaxf((float)h + offy, 0.f), 63.f);
  float x0f = floorf(ix), y0f = floorf(iy);
  float fx = ix - x0f, fy = iy - y0f;
  int x0 = (int)x0f, y0 = (int)y0f;
  int x1 = min(x0 + 1, 63), y1 = min(y0 + 1, 63);
  float g0 = (1.f - fx) * (1.f - fy), g1 = fx * (1.f - fy);
  float g2 = (1.f - fx) * fy,         g3 = fx * fy;

  const float* ma = kerb_a + (size_t)n * 25 * 4096;
  const float* mbp = kerb_b + (size_t)n * 25 * 4096;
  int c0 = y0 * 64 + x0, c1 = y0 * 64 + x1, c2 = y1 * 64 + x0, c3 = y1 * 64 + x1;

  float v0[25], v1[25], v2[25], v3[25];
#pragma unroll
  for (int k = 0; k < 25; ++k) {
    const float* mka = ma + (size_t)k * 4096;
    const float* mkb = mbp + (size_t)k * 4096;
    v0[k] = mka[c0] + mkb[c0];
    v1[k] = mka[c1] + mkb[c1];
    v2[k] = mka[c2] + mkb[c2];
    v3[k] = mka[c3] + mkb[c3];
  }
  float m0 = v0[0], m1 = v1[0], m2 = v2[0], m3 = v3[0];
#pragma unroll
  for (int k = 1; k < 25; ++k) {
    m0 = fmaxf(m0, v0[k]); m1 = fmaxf(m1, v1[k]);
    m2 = fmaxf(m2, v2[k]); m3 = fmaxf(m3, v3[k]);
  }
  float S0 = 0.f, S1 = 0.f, S2 = 0.f, S3 = 0.f;
#pragma unroll
  for (int k = 0; k < 25; ++k) {
    v0[k] = expf(v0[k] - m0); S0 += v0[k];
    v1[k] = expf(v1[k] - m1); S1 += v1[k];
    v2[k] = expf(v2[k] - m2); S2 += v2[k];
    v3[k] = expf(v3[k] - m3); S3 += v3[k];
  }
  float f0 = g0 / S0, f1 = g1 / S1, f2 = g2 / S2, f3 = g3 / S3;

  float* wp = wts + (((size_t)(n * HH + h) * 4 + pq) * 25) * 64 + w;
#pragma unroll
  for (int k = 0; k < 25; ++k)
    wp[k * 64] = v0[k] * f0 + v1[k] * f1 + v2[k] * f2 + v3[k] * f3;
}

// -------- k5: all 4 outputs per tap pass; wt[100] hoisted (R9 form, best measured) --------
__global__ __launch_bounds__(256, 2) void k5_out(const float* __restrict__ x,
                                                 const float* __restrict__ wts,
                                                 float* __restrict__ out) {
  int b = blockIdx.x;       // 1024 blocks: n(2) * h(64) * cg(8)
  int n = b >> 9;
  int r = b & 511;
  int h = r >> 3;
  int cg = r & 7;
  int wave = threadIdx.x >> 6;
  int w = threadIdx.x & 63;
  int c0 = cg * 32 + wave * 8;   // 8 channels per wave

  // hoist all 100 weights; coalesced (lane w fastest in wts layout)
  const float* wbase = wts + (size_t)(n * HH + h) * 100 * 64 + w;
  float wt[100];
#pragma unroll
  for (int i = 0; i < 100; ++i) wt[i] = wbase[i * 64];

  for (int ci = 0; ci < 8; ++ci) {
    int c = c0 + ci;
    const float* xc = x + (size_t)(n * CIN + c) * HH * WW;
    float a0 = 0.f, a1 = 0.f, a2 = 0.f, a3 = 0.f;
#pragma unroll
    for (int dy = 0; dy < 5; ++dy) {
      int rr = h + dy - 2;
      bool rok = (unsigned)rr < (unsigned)HH;
      const float* xr = xc + rr * WW;
#pragma unroll
      for (int dx = 0; dx < 5; ++dx) {
        int cc = w + dx - 2;
        float xv = (rok && (unsigned)cc < (unsigned)WW) ? xr[cc] : 0.f;
        int k = dy * 5 + dx;
        a0 += wt[k] * xv;
        a1 += wt[25 + k] * xv;
        a2 += wt[50 + k] * xv;
        a3 += wt[75 + k] * xv;
      }
    }
    float* o0 = out + ((size_t)(n * CIN + c) * HO + 2 * h) * WO + 2 * w;
    *(float2*)o0 = make_float2(a0, a1);
    *(float2*)(o0 + WO) = make_float2(a2, a3);
  }
}

extern "C" void kernel_launch(void* const* d_in, const int* in_sizes, int n_in,
                              void* d_out, int out_size, void* d_ws, size_t ws_size,
                              hipStream_t stream) {
  const float* x      = (const float*)d_in[0];
  const float* w_comp = (const float*)d_in[1];
  const float* b_comp = (const float*)d_in[2];
  const float* w_off  = (const float*)d_in[3];
  const float* b_off  = (const float*)d_in[4];
  const float* w_ker  = (const float*)d_in[5];
  const float* b_ker  = (const float*)d_in[6];
  float* out = (float*)d_out;

  float* ws       = (float*)d_ws;
  float* comp_pad = ws;
  float* offb_a   = ws + OFF_OFFA;
  float* kerb_a   = ws + OFF_KERA;
  float* offb_b   = ws + OFF_OFFB2;
  float* kerb_b   = ws + OFF_KERB2;
  float* wts      = ws + OFF_WTS;

  k1_comp<<<512, 256, 0, stream>>>(x, w_comp, b_comp, comp_pad);
  k2_conv3<<<1088, 256, 0, stream>>>(comp_pad, w_off, b_off, w_ker, b_ker,
                                     offb_a, kerb_a, offb_b, kerb_b);
  k34_wts<<<512, 64, 0, stream>>>(offb_a, offb_b, kerb_a, kerb_b, wts);
  k5_out<<<1024, 256, 0, stream>>>(x, wts, out);
}

// Round 14
// 70.860 us; speedup vs baseline: 1.3605x; 1.3605x over previous
//
#include <hip/hip_runtime.h>

#define NB 2
#define CIN 256
#define HH 64
#define WW 64
#define CCMP 64
#define HO 128
#define WO 128

// padded comp layout: [n][c][66][66], interior at (+1,+1)
#define CPLD 66
#define CPCH (CPLD * CPLD)          // 4356
#define CPIMG (CCMP * CPCH)         // 278784
#define CPTOT (NB * CPIMG)          // 557568 floats

// ws layout (floats)
#define OFF_OFFB  (CPTOT)
#define OFF_KERB  (OFF_OFFB + 65536)

// ---------------- k1: 1x1 conv -> comp_pad interior; also zeroes its halo ----------------
// 512 blocks: (n, ccg of 16, hq of 16); 4 oc/thread (2 waves/SIMD).  [R9 form]
__global__ __launch_bounds__(256) void k1_comp(const float* __restrict__ x,
                                               const float* __restrict__ wc,
                                               const float* __restrict__ bc,
                                               float* __restrict__ comp_pad) {
  int b = blockIdx.x;
  int n = b >> 8;
  int ccg = (b >> 4) & 15;
  int hq = b & 15;
  int hsub = threadIdx.x >> 6;
  int w = threadIdx.x & 63;
  int h = hq * 4 + hsub;

  float acc[4];
#pragma unroll
  for (int j = 0; j < 4; ++j) acc[j] = bc[ccg * 4 + j];
  const float* xp = x + ((size_t)(n * CIN) * HH + h) * WW + w;
#pragma unroll 4
  for (int c = 0; c < CIN; ++c) {
    float xv = xp[(size_t)c * HH * WW];
#pragma unroll
    for (int j = 0; j < 4; ++j) acc[j] += xv * wc[(ccg * 4 + j) * CIN + c];
  }
  float* plane = comp_pad + (size_t)n * CPIMG + (size_t)(ccg * 4) * CPCH;
#pragma unroll
  for (int j = 0; j < 4; ++j)
    plane[(size_t)j * CPCH + (h + 1) * CPLD + (w + 1)] = acc[j];

  // halo zeroing for this block's 4 channel planes
  if (threadIdx.x < 32) {
    int ch = threadIdx.x >> 3;
    int rw = (threadIdx.x >> 1) & 3;
    int side = threadIdx.x & 1;
    plane[(size_t)ch * CPCH + (hq * 4 + rw + 1) * CPLD + side * 65] = 0.f;
  }
  if (hq == 0)
    for (int i = threadIdx.x; i < 4 * CPLD; i += 256)
      plane[(size_t)(i / CPLD) * CPCH + (i % CPLD)] = 0.f;               // top row
  if (hq == 15)
    for (int i = threadIdx.x; i < 4 * CPLD; i += 256)
      plane[(size_t)(i / CPLD) * CPCH + 65 * CPLD + (i % CPLD)] = 0.f;   // bottom row
}

// ------------- k2: fused 3x3 convs comp_pad -> off(8ch) + ker(25ch) -------------
// 544 blocks: (n, ocp of 17, hq of 16). 2 oc/thread; reg tile t[4][9].  [R9 form]
__global__ __launch_bounds__(256) void k2_conv3(const float* __restrict__ comp_pad,
                                                const float* __restrict__ w_off,
                                                const float* __restrict__ b_off,
                                                const float* __restrict__ w_ker,
                                                const float* __restrict__ b_ker,
                                                float* __restrict__ offb,
                                                float* __restrict__ kerb) {
  int b = blockIdx.x;
  int n = b / (17 * 16);
  int r = b % (17 * 16);
  int ocp = r / 16;
  int hq = r % 16;
  int hsub = threadIdx.x >> 6;
  int w = threadIdx.x & 63;
  int h = hq * 4 + hsub;

  int oc0 = ocp * 2;
  int oc1 = (oc0 + 1 < 33) ? oc0 + 1 : 32;
  const float* wp0 = (oc0 < 8) ? (w_off + (size_t)oc0 * CCMP * 9)
                               : (w_ker + (size_t)(oc0 - 8) * CCMP * 9);
  const float* wp1 = (oc1 < 8) ? (w_off + (size_t)oc1 * CCMP * 9)
                               : (w_ker + (size_t)(oc1 - 8) * CCMP * 9);
  float a0 = (oc0 < 8) ? b_off[oc0] : b_ker[oc0 - 8];
  float a1 = (oc1 < 8) ? b_off[oc1] : b_ker[oc1 - 8];

  const float* base = comp_pad + (size_t)n * CPIMG + h * CPLD + w;

  for (int cb = 0; cb < CCMP; cb += 4) {
    float t[4][9];
#pragma unroll
    for (int cc = 0; cc < 4; ++cc) {
      const float* p = base + (size_t)(cb + cc) * CPCH;
#pragma unroll
      for (int dy = 0; dy < 3; ++dy)
#pragma unroll
        for (int dx = 0; dx < 3; ++dx)
          t[cc][dy * 3 + dx] = p[dy * CPLD + dx];
    }
#pragma unroll
    for (int cc = 0; cc < 4; ++cc)
#pragma unroll
      for (int k = 0; k < 9; ++k) {
        float tv = t[cc][k];
        a0 += tv * wp0[(cb + cc) * 9 + k];
        a1 += tv * wp1[(cb + cc) * 9 + k];
      }
  }

  int pos = h * WW + w;
  if (oc0 < 8) offb[(size_t)(n * 8 + oc0) * 4096 + pos] = a0;
  else         kerb[(size_t)(n * 25 + (oc0 - 8)) * 4096 + pos] = a0;
  if (oc1 < 8) offb[(size_t)(n * 8 + oc1) * 4096 + pos] = a1;
  else         kerb[(size_t)(n * 25 + (oc1 - 8)) * 4096 + pos] = a1;
}

// ------- k345: fused softmax+sample (phase A, LDS) + dynamic upsample (phase B) -------
// 256 blocks x 512 threads: (n, h, cg2 of 2). Phase A computed per (n,h) row (2x dup).
__global__ __launch_bounds__(512) void k345(const float* __restrict__ x,
                                            const float* __restrict__ offb,
                                            const float* __restrict__ kerb,
                                            float* __restrict__ out) {
  __shared__ float wl[100][64];       // [pq*25+k][w], 25.6 KB
  int b = blockIdx.x;
  int n = b >> 7;
  int h = (b >> 1) & 63;
  int cg2 = b & 1;
  int tid = threadIdx.x;

  if (tid < 256) {
    int w = tid & 63, pq = tid >> 6;
    float offx = offb[((size_t)(n * 8 + pq) * HH + h) * WW + w];
    float offy = offb[((size_t)(n * 8 + 4 + pq) * HH + h) * WW + w];
    // align_corners=True + border clamp algebra: sample at (h+offy, w+offx)
    float ix = fminf(fmaxf((float)w + offx, 0.f), 63.f);
    float iy = fminf(fmaxf((float)h + offy, 0.f), 63.f);
    float x0f = floorf(ix), y0f = floorf(iy);
    float fx = ix - x0f, fy = iy - y0f;
    int x0 = (int)x0f, y0 = (int)y0f;
    int x1 = min(x0 + 1, 63), y1 = min(y0 + 1, 63);
    float g0 = (1.f - fx) * (1.f - fy), g1 = fx * (1.f - fy);
    float g2 = (1.f - fx) * fy,         g3 = fx * fy;

    const float* mb = kerb + (size_t)n * 25 * 4096;
    int c0 = y0 * 64 + x0, c1 = y0 * 64 + x1, c2 = y1 * 64 + x0, c3 = y1 * 64 + x1;

    float v0[25], v1[25], v2[25], v3[25];
#pragma unroll
    for (int k = 0; k < 25; ++k) {
      const float* mk = mb + (size_t)k * 4096;
      v0[k] = mk[c0]; v1[k] = mk[c1]; v2[k] = mk[c2]; v3[k] = mk[c3];
    }
    float m0 = v0[0], m1 = v1[0], m2 = v2[0], m3 = v3[0];
#pragma unroll
    for (int k = 1; k < 25; ++k) {
      m0 = fmaxf(m0, v0[k]); m1 = fmaxf(m1, v1[k]);
      m2 = fmaxf(m2, v2[k]); m3 = fmaxf(m3, v3[k]);
    }
    float S0 = 0.f, S1 = 0.f, S2 = 0.f, S3 = 0.f;
#pragma unroll
    for (int k = 0; k < 25; ++k) {
      v0[k] = expf(v0[k] - m0); S0 += v0[k];
      v1[k] = expf(v1[k] - m1); S1 += v1[k];
      v2[k] = expf(v2[k] - m2); S2 += v2[k];
      v3[k] = expf(v3[k] - m3); S3 += v3[k];
    }
    float f0 = g0 / S0, f1 = g1 / S1, f2 = g2 / S2, f3 = g3 / S3;
#pragma unroll
    for (int k = 0; k < 25; ++k)
      wl[pq * 25 + k][w] = v0[k] * f0 + v1[k] * f1 + v2[k] * f2 + v3[k] * f3;
  }
  __syncthreads();

  int wave = tid >> 6;
  int w = tid & 63;
  float wt[100];
#pragma unroll
  for (int i = 0; i < 100; ++i) wt[i] = wl[i][w];   // consecutive lane addrs: conflict-free

  int ch0 = cg2 * 128 + wave * 16;
  for (int ci = 0; ci < 16; ++ci) {
    int c = ch0 + ci;
    const float* xc = x + (size_t)(n * CIN + c) * HH * WW;
    float a0 = 0.f, a1 = 0.f, a2 = 0.f, a3 = 0.f;
#pragma unroll
    for (int dy = 0; dy < 5; ++dy) {
      int rr = h + dy - 2;
      bool rok = (unsigned)rr < (unsigned)HH;
      const float* xr = xc + rr * WW;
#pragma unroll
      for (int dx = 0; dx < 5; ++dx) {
        int cc = w + dx - 2;
        float xv = (rok && (unsigned)cc < (unsigned)WW) ? xr[cc] : 0.f;
        int k = dy * 5 + dx;
        a0 += wt[k] * xv;
        a1 += wt[25 + k] * xv;
        a2 += wt[50 + k] * xv;
        a3 += wt[75 + k] * xv;
      }
    }
    float* o0 = out + ((size_t)(n * CIN + c) * HO + 2 * h) * WO + 2 * w;
    *(float2*)o0 = make_float2(a0, a1);
    *(float2*)(o0 + WO) = make_float2(a2, a3);
  }
}

extern "C" void kernel_launch(void* const* d_in, const int* in_sizes, int n_in,
                              void* d_out, int out_size, void* d_ws, size_t ws_size,
                              hipStream_t stream) {
  const float* x      = (const float*)d_in[0];
  const float* w_comp = (const float*)d_in[1];
  const float* b_comp = (const float*)d_in[2];
  const float* w_off  = (const float*)d_in[3];
  const float* b_off  = (const float*)d_in[4];
  const float* w_ker  = (const float*)d_in[5];
  const float* b_ker  = (const float*)d_in[6];
  float* out = (float*)d_out;

  float* ws       = (float*)d_ws;
  float* comp_pad = ws;
  float* offb     = ws + OFF_OFFB;
  float* kerb     = ws + OFF_KERB;   // raw conv output (softmax fused into k345)

  k1_comp<<<512, 256, 0, stream>>>(x, w_comp, b_comp, comp_pad);
  k2_conv3<<<544, 256, 0, stream>>>(comp_pad, w_off, b_off, w_ker, b_ker, offb, kerb);
  k345<<<256, 512, 0, stream>>>(x, offb, kerb, out);
}